// Round 10
// baseline (274.557 us; speedup 1.0000x reference)
//
#include <hip/hip_runtime.h>
#include <hip/hip_bf16.h>
#include <math.h>

// T5 encoder block on MI355X (gfx950). B=2, S=1024, D_MODEL=1024, H=16,
// D_KV=64, D_FF=4096. Harness buffers fp32. Internal bf16 MFMA, fp32 acc.
// ROUND 10: drop weight pre-convert (fp32-W staging in-GEMM; saves 48 MB
// HBM + a serial launch), GEMM __launch_bounds__(256,3) for 3 blocks/CU
// barrier overlap, bias_table merged into RMSNorm prologue, WO split-K=2.

typedef __bf16 bf16_t;
typedef __attribute__((ext_vector_type(8))) __bf16 bf16x8;
typedef __attribute__((ext_vector_type(4))) __bf16 bf16x4;
typedef __attribute__((ext_vector_type(4))) float floatx4;

#define GLOBAL_AS(p) ((const __attribute__((address_space(1))) void*)(p))
#define LDS_AS(p)    ((__attribute__((address_space(3))) void*)(p))

// ---------------------------------------------------------------------------
// Prologue: blocks [0,2048) = RMSNorm rows of hs -> x (bf16);
//           blocks [2048,2176) = rel-pos bias table (128 blocks x 256).
// ---------------------------------------------------------------------------
__global__ __launch_bounds__(256) void prologue_kernel(
    const float* __restrict__ hs, const float* __restrict__ ln1w,
    const float* __restrict__ rel_bias, bf16_t* __restrict__ x,
    float* __restrict__ table) {
  int bid = blockIdx.x;
  int t = threadIdx.x;
  if (bid < 2048) {
    const int D = 1024;
    float4 v = ((const float4*)(hs + (size_t)bid * D))[t];
    float f[4] = {v.x, v.y, v.z, v.w};
    float s = 0.f;
#pragma unroll
    for (int j = 0; j < 4; ++j) s += f[j] * f[j];
#pragma unroll
    for (int off = 32; off > 0; off >>= 1) s += __shfl_down(s, off);
    __shared__ float red[4];
    int lane = t & 63, wave = t >> 6;
    if (lane == 0) red[wave] = s;
    __syncthreads();
    float tot = red[0] + red[1] + red[2] + red[3];
    float scale = rsqrtf(tot * (1.0f / D) + 1e-6f);
    float4 wv4 = ((const float4*)ln1w)[t];
    bf16x4 o;
    o[0] = (bf16_t)(f[0] * scale * wv4.x);
    o[1] = (bf16_t)(f[1] * scale * wv4.y);
    o[2] = (bf16_t)(f[2] * scale * wv4.z);
    o[3] = (bf16_t)(f[3] * scale * wv4.w);
    *(bf16x4*)(x + (size_t)bid * D + t * 4) = o;
  } else {
    int idx = (bid - 2048) * 256 + t;
    int h = idx >> 11;
    int dpos = idx & 2047;
    int delta = dpos - 1023;
    if (delta > 1023) delta = 1023;
    int side = (delta > 0) ? 16 : 0;
    int rp = (delta < 0) ? -delta : delta;
    int bucket;
    if (rp < 8) {
      bucket = side + rp;
    } else {
      float t3 = (logf((float)rp * 0.125f) / 2.7725887f) * 8.0f;
      int v = 8 + (int)t3;
      if (v > 15) v = 15;
      bucket = side + v;
    }
    table[idx] = rel_bias[bucket * 16 + h];
  }
}

// ---------------------------------------------------------------------------
// GEMM: C[M,N] = epilogue(A[M,K] @ W[N,K]^T over K-slice blockIdx.z).
// TBM in {64,128}, BN=128, BK=64, 4 waves (2x2), wave tile (TBM/2)x64.
// A: bf16, DMA-staged with source-side XOR swizzle (dest linear).
// W: fp32, staged through VGPRs with cvt->bf16, same XOR-swizzled layout
//    (store to physical chunk p; p holds source k-chunk p^(row&7)).
// Fragment read: physical chunk (c*4+lq)^(row&7) -> source chunk c*4+lq.
// W0/W1/W2 3-way select by output col (QKV fusion; wsel_cols=1<<30 to off).
// OP: 0 = store, 2 = relu-store.  Output bf16 at C + z*M*N.
// XCD stripe swizzle (needs gridDim.y % 8 == 0 -- true for all launches).
// ---------------------------------------------------------------------------
template <int TBM, int OP>
__global__ __launch_bounds__(256, 3) void gemm_bt(
    const bf16_t* __restrict__ A, const float* __restrict__ W0,
    const float* __restrict__ W1, const float* __restrict__ W2,
    bf16_t* __restrict__ C, int M, int K_total, int klen, int N,
    int wsel_cols) {
  constexpr int MFRAG = TBM / 32;
  __shared__ bf16_t As[TBM * 64];
  __shared__ bf16_t Bs[128 * 64];

  const int tid = threadIdx.x;
  const int lane = tid & 63;
  const int wv = tid >> 6;
  const int wm = wv & 1;
  const int wn = wv >> 1;
  const int lr = lane & 15;
  const int lq = lane >> 4;

  int bx = blockIdx.x, by = blockIdx.y;
  {
    int gx = gridDim.x, gy = gridDim.y;
    int lid = by * gx + bx;
    int xcd = lid & 7, slot = lid >> 3;
    int per = gy >> 3;
    by = xcd * per + slot % per;
    bx = slot / per;
  }

  const size_t row0 = (size_t)bx * TBM;
  const size_t col0 = (size_t)by * 128;
  const int k0 = blockIdx.z * klen;

  const float* Ws = W0;
  size_t wc0 = col0;
  if ((int)col0 >= wsel_cols) {
    if ((int)col0 < 2 * wsel_cols) { Ws = W1; wc0 = col0 - wsel_cols; }
    else { Ws = W2; wc0 = col0 - 2 * (size_t)wsel_cols; }
  }

  const bf16_t* Abase = A + row0 * K_total;
  const float* Wbase = Ws + wc0 * K_total;
  bf16_t* Cs = C + (size_t)blockIdx.z * M * N;

  floatx4 acc[MFRAG][4] = {};

  for (int kt = k0; kt < k0 + klen; kt += 64) {
    // A: TBM rows x 64 cols = TBM*8 chunks of 16B, DMA with src-side swizzle
#pragma unroll
    for (int i = 0; i < TBM / 32; ++i) {
      int chunk = i * 256 + tid;
      int r = chunk >> 3;
      int kc = ((chunk & 7) ^ (r & 7)) << 3;
      __builtin_amdgcn_global_load_lds(
          GLOBAL_AS(Abase + (size_t)r * K_total + kt + kc),
          LDS_AS(As + (size_t)(i * 256 + wv * 64) * 8), 16, 0, 0);
    }
    // W: fp32 -> bf16 through VGPRs, same swizzled layout
#pragma unroll
    for (int i = 0; i < 4; ++i) {
      int chunk = i * 256 + tid;
      int r = chunk >> 3;
      int kc = ((chunk & 7) ^ (r & 7)) << 3;
      const float* p = Wbase + (size_t)r * K_total + kt + kc;
      float4 f0 = *(const float4*)p;
      float4 f1v = *(const float4*)(p + 4);
      bf16x8 o;
      o[0] = (bf16_t)f0.x; o[1] = (bf16_t)f0.y;
      o[2] = (bf16_t)f0.z; o[3] = (bf16_t)f0.w;
      o[4] = (bf16_t)f1v.x; o[5] = (bf16_t)f1v.y;
      o[6] = (bf16_t)f1v.z; o[7] = (bf16_t)f1v.w;
      *(bf16x8*)(Bs + chunk * 8) = o;
    }
    __syncthreads();

#pragma unroll
    for (int c = 0; c < 2; ++c) {
      bf16x8 af[MFRAG], bfr[4];
#pragma unroll
      for (int mi = 0; mi < MFRAG; ++mi) {
        int rr = wm * (TBM / 2) + mi * 16 + lr;
        int c8p = (c * 4 + lq) ^ (rr & 7);
        af[mi] = *(const bf16x8*)(As + rr * 64 + c8p * 8);
      }
#pragma unroll
      for (int nj = 0; nj < 4; ++nj) {
        int rr = wn * 64 + nj * 16 + lr;
        int c8p = (c * 4 + lq) ^ (rr & 7);
        bfr[nj] = *(const bf16x8*)(Bs + rr * 64 + c8p * 8);
      }
#pragma unroll
      for (int mi = 0; mi < MFRAG; ++mi)
#pragma unroll
        for (int nj = 0; nj < 4; ++nj)
          acc[mi][nj] = __builtin_amdgcn_mfma_f32_16x16x32_bf16(
              af[mi], bfr[nj], acc[mi][nj], 0, 0, 0);
    }
    __syncthreads();
  }

#pragma unroll
  for (int mi = 0; mi < MFRAG; ++mi) {
#pragma unroll
    for (int nj = 0; nj < 4; ++nj) {
      size_t r = row0 + wm * (TBM / 2) + mi * 16 + lq * 4;
      size_t c = col0 + wn * 64 + nj * 16 + lr;
#pragma unroll
      for (int t = 0; t < 4; ++t) {
        float v = acc[mi][nj][t];
        if (OP == 2) v = v > 0.f ? v : 0.f;
        Cs[(r + t) * N + c] = (bf16_t)v;
      }
    }
  }
}

// ---------------------------------------------------------------------------
// V transpose: qkv V-section [b,s,h,d] -> Vt_g[(b*16+h)*64 + d][s].
// ---------------------------------------------------------------------------
__global__ __launch_bounds__(256) void transpose_v_kernel(
    const bf16_t* __restrict__ QKV, bf16_t* __restrict__ VT) {
  __shared__ bf16_t T[64 * 65];
  const int s0 = blockIdx.x * 64;
  const int h = blockIdx.y;
  const int b = blockIdx.z;
  const int tid = threadIdx.x;

  const bf16_t* Vh = QKV + ((size_t)b * 1024) * 3072 + 2048 + h * 64;
#pragma unroll
  for (int i = 0; i < 2; ++i) {
    int c = i * 256 + tid;
    int r = c >> 3;
    int d8 = (c & 7) * 8;
    bf16x8 v = *(const bf16x8*)(Vh + (size_t)(s0 + r) * 3072 + d8);
#pragma unroll
    for (int j = 0; j < 8; ++j) T[r * 65 + d8 + j] = v[j];
  }
  __syncthreads();

  bf16_t* Og = VT + ((size_t)b * 16 + h) * 64 * 1024;
#pragma unroll
  for (int i = 0; i < 2; ++i) {
    int c = i * 256 + tid;
    int d = c >> 3;
    int s8 = (c & 7) * 8;
    bf16x8 o;
#pragma unroll
    for (int j = 0; j < 8; ++j) o[j] = T[(s8 + j) * 65 + d];
    *(bf16x8*)(Og + (size_t)d * 1024 + s0 + s8) = o;
  }
}

// ---------------------------------------------------------------------------
// Flash attention, T5 style.  Fragment-major LDS (conflict-free), S^T MFMA,
// constant-shift softmax.
// ---------------------------------------------------------------------------
__device__ __forceinline__ void attn_stage(const bf16_t* Kh, const bf16_t* Vg,
                                           int k0, bf16_t* Ksb, bf16_t* Vtb,
                                           int tid, int wv) {
  const int l16 = tid & 15;
  const int lo8 = ((tid & 63) >> 4) * 8;
#pragma unroll
  for (int i = 0; i < 2; ++i) {
    int bi = wv * 2 + i;
    int g = bi >> 1, c = bi & 1;
    __builtin_amdgcn_global_load_lds(
        GLOBAL_AS(Kh + (size_t)(k0 + g * 16 + l16) * 3072 + c * 32 + lo8),
        LDS_AS(Ksb + bi * 512), 16, 0, 0);
    __builtin_amdgcn_global_load_lds(
        GLOBAL_AS(Vg + (size_t)(g * 16 + l16) * 1024 + k0 + c * 32 + lo8),
        LDS_AS(Vtb + bi * 512), 16, 0, 0);
  }
}

__global__ __launch_bounds__(256) void attn_kernel(
    const bf16_t* __restrict__ QKV, const bf16_t* __restrict__ VT,
    const float* __restrict__ bias_table, bf16_t* __restrict__ O) {
  const int qt = blockIdx.x;
  const int h = blockIdx.y;
  const int b = blockIdx.z;
  const int tid = threadIdx.x;
  const int lane = tid & 63;
  const int wv = tid >> 6;
  const int lr = lane & 15;
  const int lq = lane >> 4;

  __shared__ bf16_t Ks[2][4096];
  __shared__ bf16_t Vt[2][4096];
  __shared__ bf16_t Ps[4][1024];

  const bf16_t* Qh = QKV + (size_t)b * 1024 * 3072 + h * 64;
  const bf16_t* Kh = Qh + 1024;
  const bf16_t* Vg = VT + ((size_t)b * 16 + h) * 64 * 1024;
  bf16_t* Oh = O + (size_t)b * 1024 * 1024 + h * 64;

  const int q0w = qt * 64 + wv * 16;
  const int myq = q0w + lr;

  bf16x8 qf[2];
#pragma unroll
  for (int c = 0; c < 2; ++c)
    qf[c] = *(const bf16x8*)(Qh + (size_t)(q0w + lr) * 3072 + c * 32 + lq * 8);

  float l_loc = 0.f;
  floatx4 o_acc[4];
#pragma unroll
  for (int i = 0; i < 4; ++i) o_acc[i] = (floatx4){0.f, 0.f, 0.f, 0.f};

  const float* btab = bias_table + h * 2048 + 1023 - myq;

  attn_stage(Kh, Vg, 0, Ks[0], Vt[0], tid, wv);
  __syncthreads();

  for (int kt = 0; kt < 16; ++kt) {
    const int k0 = kt * 64;
    if (kt < 15)
      attn_stage(Kh, Vg, k0 + 64, Ks[(kt + 1) & 1], Vt[(kt + 1) & 1], tid, wv);
    const bf16_t* Ksb = Ks[kt & 1];
    const bf16_t* Vtb = Vt[kt & 1];

    floatx4 s_acc[4];
#pragma unroll
    for (int g = 0; g < 4; ++g) {
      floatx4 a = (floatx4){0.f, 0.f, 0.f, 0.f};
#pragma unroll
      for (int c = 0; c < 2; ++c) {
        bf16x8 kf = *(const bf16x8*)(Ksb + (g * 2 + c) * 512 + lane * 8);
        a = __builtin_amdgcn_mfma_f32_16x16x32_bf16(kf, qf[c], a, 0, 0, 0);
      }
      s_acc[g] = a;
    }

#pragma unroll
    for (int g = 0; g < 4; ++g) {
      bf16x4 pb;
#pragma unroll
      for (int t = 0; t < 4; ++t) {
        int key = k0 + g * 16 + lq * 4 + t;
        float p = __expf(s_acc[g][t] + btab[key] - 32.0f);
        l_loc += p;
        pb[t] = (bf16_t)p;
      }
      int c = g >> 1;
      int dst = c * 512 + (((g & 1) * 2 + (lq >> 1)) * 16 + lr) * 8 + (lq & 1) * 4;
      *(bf16x4*)(&Ps[wv][dst]) = pb;
    }

    asm volatile("s_waitcnt lgkmcnt(0)" ::: "memory");

    bf16x8 pf[2];
#pragma unroll
    for (int c = 0; c < 2; ++c)
      pf[c] = *(const bf16x8*)(&Ps[wv][c * 512 + lane * 8]);

#pragma unroll
    for (int g = 0; g < 4; ++g) {
#pragma unroll
      for (int c = 0; c < 2; ++c) {
        bf16x8 vf = *(const bf16x8*)(Vtb + (g * 2 + c) * 512 + lane * 8);
        o_acc[g] = __builtin_amdgcn_mfma_f32_16x16x32_bf16(pf[c], vf, o_acc[g], 0, 0, 0);
      }
    }
    __syncthreads();
  }

  l_loc += __shfl_xor(l_loc, 16);
  l_loc += __shfl_xor(l_loc, 32);
  float inv = 1.f / l_loc;

  float invt[4];
#pragma unroll
  for (int t = 0; t < 4; ++t) invt[t] = __shfl(inv, lq * 4 + t);

#pragma unroll
  for (int g = 0; g < 4; ++g) {
#pragma unroll
    for (int t = 0; t < 4; ++t) {
      int qg = q0w + lq * 4 + t;
      int d = g * 16 + lr;
      Oh[(size_t)qg * 1024 + d] = (bf16_t)(o_acc[g][t] * invt[t]);
    }
  }
}

// ---------------------------------------------------------------------------
// Split-K reduce + fp32 residual + fused RMSNorm.
// ---------------------------------------------------------------------------
__global__ __launch_bounds__(256) void reduce_rms_kernel(
    const bf16_t* __restrict__ part, int splits, const float* __restrict__ hs,
    const float* __restrict__ ln2w, bf16_t* __restrict__ hbuf,
    bf16_t* __restrict__ y) {
  const size_t SLICE = (size_t)2048 * 1024;
  int tid = threadIdx.x;
  size_t i = ((size_t)blockIdx.x * 256 + tid) * 8;

  float s[8] = {};
  for (int sp = 0; sp < splits; ++sp) {
    bf16x8 p = *(const bf16x8*)(part + sp * SLICE + i);
#pragma unroll
    for (int j = 0; j < 8; ++j) s[j] += (float)p[j];
  }
  float4 a = *(const float4*)(hs + i);
  float4 b = *(const float4*)(hs + i + 4);
  s[0] += a.x; s[1] += a.y; s[2] += a.z; s[3] += a.w;
  s[4] += b.x; s[5] += b.y; s[6] += b.z; s[7] += b.w;

  bf16x8 hb;
#pragma unroll
  for (int j = 0; j < 8; ++j) hb[j] = (bf16_t)s[j];
  *(bf16x8*)(hbuf + i) = hb;

  float ss = 0.f;
#pragma unroll
  for (int j = 0; j < 8; ++j) ss += s[j] * s[j];
#pragma unroll
  for (int off = 32; off > 0; off >>= 1) ss += __shfl_down(ss, off);
  __shared__ float red[4];
  int wave = tid >> 6;
  if ((tid & 63) == 0) red[wave] = ss;
  __syncthreads();
  float rowss = (tid < 128) ? (red[0] + red[1]) : (red[2] + red[3]);
  float scale = rsqrtf(rowss * (1.f / 1024.f) + 1e-6f);

  int col = (int)(i & 1023);
  float4 w0 = *(const float4*)(ln2w + col);
  float4 w1 = *(const float4*)(ln2w + col + 4);
  bf16x8 o;
  o[0] = (bf16_t)(s[0] * scale * w0.x); o[1] = (bf16_t)(s[1] * scale * w0.y);
  o[2] = (bf16_t)(s[2] * scale * w0.z); o[3] = (bf16_t)(s[3] * scale * w0.w);
  o[4] = (bf16_t)(s[4] * scale * w1.x); o[5] = (bf16_t)(s[5] * scale * w1.y);
  o[6] = (bf16_t)(s[6] * scale * w1.z); o[7] = (bf16_t)(s[7] * scale * w1.w);
  *(bf16x8*)(y + i) = o;
}

// ---------------------------------------------------------------------------
// Final split-K reduce + bf16 residual -> fp32 output.
// ---------------------------------------------------------------------------
__global__ __launch_bounds__(256) void reduce_out_kernel(
    const bf16_t* __restrict__ part, int splits,
    const bf16_t* __restrict__ res, float* __restrict__ out) {
  const size_t SLICE = (size_t)2048 * 1024;
  size_t i = ((size_t)blockIdx.x * 256 + threadIdx.x) * 8;
  float s[8] = {};
  for (int sp = 0; sp < splits; ++sp) {
    bf16x8 p = *(const bf16x8*)(part + sp * SLICE + i);
#pragma unroll
    for (int j = 0; j < 8; ++j) s[j] += (float)p[j];
  }
  bf16x8 r = *(const bf16x8*)(res + i);
#pragma unroll
  for (int j = 0; j < 8; ++j) s[j] += (float)r[j];
  float4 a, b;
  a.x = s[0]; a.y = s[1]; a.z = s[2]; a.w = s[3];
  b.x = s[4]; b.y = s[5]; b.z = s[6]; b.w = s[7];
  *(float4*)(out + i) = a;
  *(float4*)(out + i + 4) = b;
}

// ---------------------------------------------------------------------------
extern "C" void kernel_launch(void* const* d_in, const int* in_sizes, int n_in,
                              void* d_out, int out_size, void* d_ws,
                              size_t ws_size, hipStream_t stream) {
  const float* hs = (const float*)d_in[0];
  const float* ln1_w = (const float*)d_in[1];
  const float* wq = (const float*)d_in[2];
  const float* wk = (const float*)d_in[3];
  const float* wvv = (const float*)d_in[4];
  const float* wo = (const float*)d_in[5];
  const float* rel_bias = (const float*)d_in[6];
  const float* ln2_w = (const float*)d_in[7];
  const float* wi = (const float*)d_in[8];
  const float* wo_ff = (const float*)d_in[9];
  float* out = (float*)d_out;

  const int M = 2048, D = 1024, FF = 4096;
  const size_t SL = (size_t)M * D * 2;       // 4 MB
  const size_t QKVB = (size_t)M * 3072 * 2;  // 12 MB
  const size_t F1B = (size_t)M * FF * 2;     // 16 MB
  const size_t BT = 16 * 2048 * 4;           // 128 KB

  // FULL: btab|x|qkv|ctx|hbuf|y|f1|vtg|part(4) = 64.1 MB
  const size_t FULL_NEED = BT + SL + QKVB + SL + SL + SL + F1B + SL + 4 * SL;
  const size_t COMPACT_NEED = BT + SL + QKVB + F1B;  // 33,685,504 (proven)

  char* w = (char*)d_ws;
  dim3 gtv(16, 16, 2), ga(16, 16, 2);

  if (ws_size >= FULL_NEED) {
    float* btab = (float*)w;   w += BT;
    bf16_t* x = (bf16_t*)w;    w += SL;
    bf16_t* qkv = (bf16_t*)w;  w += QKVB;
    bf16_t* ctx = (bf16_t*)w;  w += SL;
    bf16_t* hbuf = (bf16_t*)w; w += SL;
    bf16_t* y = (bf16_t*)w;    w += SL;
    bf16_t* f1 = (bf16_t*)w;   w += F1B;
    bf16_t* vtg = (bf16_t*)w;  w += SL;
    bf16_t* part = (bf16_t*)w; w += 4 * SL;

    // RMSNorm(hs) + bias table in one launch
    prologue_kernel<<<2176, 256, 0, stream>>>(hs, ln1_w, rel_bias, x, btab);

    // QKV: 128-tile, (16,24) = 384 blocks, fp32 W 3-way select
    gemm_bt<128, 0><<<dim3(16, 24, 1), 256, 0, stream>>>(
        x, wq, wk, wvv, qkv, M, D, D, 3072, 1024);
    transpose_v_kernel<<<gtv, 256, 0, stream>>>(qkv, vtg);
    attn_kernel<<<ga, 256, 0, stream>>>(qkv, vtg, btab, ctx);

    // WO: 128-tile split-K=2 -> (16,8,2) = 256 blocks, K=512 -> 8 iters
    gemm_bt<128, 0><<<dim3(16, 8, 2), 256, 0, stream>>>(
        ctx, wo, wo, wo, part, M, D, D / 2, D, 1 << 30);
    reduce_rms_kernel<<<1024, 256, 0, stream>>>(part, 2, hs, ln2_w, hbuf, y);

    // WI: 128-tile, (16,32) = 512 blocks
    gemm_bt<128, 2><<<dim3(16, 32, 1), 256, 0, stream>>>(
        y, wi, wi, wi, f1, M, D, D, FF, 1 << 30);

    // WO_FF: 128-tile split-K=4 -> (16,8,4) = 512 blocks, K=1024 -> 16 iters
    gemm_bt<128, 0><<<dim3(16, 8, 4), 256, 0, stream>>>(
        f1, wo_ff, wo_ff, wo_ff, part, M, FF, FF / 4, D, 1 << 30);
    reduce_out_kernel<<<1024, 256, 0, stream>>>(part, 4, hbuf, out);
  } else {
    if (ws_size < COMPACT_NEED) return;
    float* btab = (float*)w;  w += BT;
    char* Abuf = w;           w += SL;
    char* Bbuf = w;           w += QKVB;
    char* Fbuf = w;           w += F1B;
    bf16_t* x = (bf16_t*)Abuf;
    bf16_t* ctx = (bf16_t*)Abuf;
    bf16_t* hbuf = (bf16_t*)Abuf;
    bf16_t* qkv = (bf16_t*)Bbuf;
    bf16_t* part = (bf16_t*)Bbuf;
    bf16_t* y = (bf16_t*)(Bbuf + 2 * SL);
    bf16_t* vtg = (bf16_t*)Fbuf;
    bf16_t* f1 = (bf16_t*)Fbuf;

    prologue_kernel<<<2176, 256, 0, stream>>>(hs, ln1_w, rel_bias, x, btab);

    gemm_bt<64, 0><<<dim3(32, 24, 1), 256, 0, stream>>>(
        x, wq, wk, wvv, qkv, M, D, D, 3072, 1024);
    transpose_v_kernel<<<gtv, 256, 0, stream>>>(qkv, vtg);
    attn_kernel<<<ga, 256, 0, stream>>>(qkv, vtg, btab, ctx);

    gemm_bt<64, 0><<<dim3(32, 8, 2), 256, 0, stream>>>(
        ctx, wo, wo, wo, part, M, D, D / 2, D, 1 << 30);
    reduce_rms_kernel<<<1024, 256, 0, stream>>>(part, 2, hs, ln2_w, hbuf, y);

    gemm_bt<64, 2><<<dim3(32, 32, 1), 256, 0, stream>>>(
        y, wi, wi, wi, f1, M, D, D, FF, 1 << 30);

    gemm_bt<64, 0><<<dim3(32, 8, 2), 256, 0, stream>>>(
        f1, wo_ff, wo_ff, wo_ff, part, M, FF, FF / 2, D, 1 << 30);
    reduce_out_kernel<<<1024, 256, 0, stream>>>(part, 2, hbuf, out);
  }
}

// Round 11
// 232.980 us; speedup vs baseline: 1.1785x; 1.1785x over previous
//
#include <hip/hip_runtime.h>
#include <hip/hip_bf16.h>
#include <math.h>

// T5 encoder block on MI355X (gfx950). B=2, S=1024, D_MODEL=1024, H=16,
// D_KV=64, D_FF=4096. Harness buffers fp32 (ws=256MiB -> full plan).
// Internal bf16 MFMA, fp32 acc.
// ROUND 11: revert round-10's fp32-W staging regression (restore weight
// pre-convert + bf16 W DMA staging; W bytes are multiplied by tile reuse,
// so converting once is strictly cheaper). Keep prologue merge and
// __launch_bounds__(256,3) (32KB LDS -> 3 blocks/CU fits).

typedef __bf16 bf16_t;
typedef __attribute__((ext_vector_type(8))) __bf16 bf16x8;
typedef __attribute__((ext_vector_type(4))) __bf16 bf16x4;
typedef __attribute__((ext_vector_type(4))) float floatx4;

#define GLOBAL_AS(p) ((const __attribute__((address_space(1))) void*)(p))
#define LDS_AS(p)    ((__attribute__((address_space(3))) void*)(p))

// ---------------------------------------------------------------------------
// Weights fp32 -> bf16 (full plan). wqkv_b packs [wq;wk;wv] as [3072,1024].
// ---------------------------------------------------------------------------
__global__ __launch_bounds__(256) void convert_w_kernel(
    const float* __restrict__ wq, const float* __restrict__ wk,
    const float* __restrict__ wv, const float* __restrict__ wo,
    const float* __restrict__ wi, const float* __restrict__ woff,
    bf16_t* __restrict__ wqkv_b, bf16_t* __restrict__ wo_b,
    bf16_t* __restrict__ wi_b, bf16_t* __restrict__ woff_b) {
  size_t idx = ((size_t)blockIdx.x * 256 + threadIdx.x) * 8;
  const float* src;
  bf16_t* dst;
  size_t off;
  if (idx < 3145728) {
    size_t sec = idx >> 20;
    src = sec == 0 ? wq : (sec == 1 ? wk : wv);
    dst = wqkv_b + (sec << 20);
    off = idx & 1048575;
  } else if (idx < 4194304) {
    src = wo; dst = wo_b; off = idx - 3145728;
  } else if (idx < 8388608) {
    src = wi; dst = wi_b; off = idx - 4194304;
  } else {
    src = woff; dst = woff_b; off = idx - 8388608;
  }
  float4 a = *(const float4*)(src + off);
  float4 b = *(const float4*)(src + off + 4);
  bf16x8 o;
  o[0] = (bf16_t)a.x; o[1] = (bf16_t)a.y; o[2] = (bf16_t)a.z; o[3] = (bf16_t)a.w;
  o[4] = (bf16_t)b.x; o[5] = (bf16_t)b.y; o[6] = (bf16_t)b.z; o[7] = (bf16_t)b.w;
  *(bf16x8*)(dst + off) = o;
}

// ---------------------------------------------------------------------------
// Prologue: blocks [0,2048) = RMSNorm rows of hs -> x (bf16);
//           blocks [2048,2176) = rel-pos bias table.
// ---------------------------------------------------------------------------
__global__ __launch_bounds__(256) void prologue_kernel(
    const float* __restrict__ hs, const float* __restrict__ ln1w,
    const float* __restrict__ rel_bias, bf16_t* __restrict__ x,
    float* __restrict__ table) {
  int bid = blockIdx.x;
  int t = threadIdx.x;
  if (bid < 2048) {
    const int D = 1024;
    float4 v = ((const float4*)(hs + (size_t)bid * D))[t];
    float f[4] = {v.x, v.y, v.z, v.w};
    float s = 0.f;
#pragma unroll
    for (int j = 0; j < 4; ++j) s += f[j] * f[j];
#pragma unroll
    for (int off = 32; off > 0; off >>= 1) s += __shfl_down(s, off);
    __shared__ float red[4];
    int lane = t & 63, wave = t >> 6;
    if (lane == 0) red[wave] = s;
    __syncthreads();
    float tot = red[0] + red[1] + red[2] + red[3];
    float scale = rsqrtf(tot * (1.0f / D) + 1e-6f);
    float4 wv4 = ((const float4*)ln1w)[t];
    bf16x4 o;
    o[0] = (bf16_t)(f[0] * scale * wv4.x);
    o[1] = (bf16_t)(f[1] * scale * wv4.y);
    o[2] = (bf16_t)(f[2] * scale * wv4.z);
    o[3] = (bf16_t)(f[3] * scale * wv4.w);
    *(bf16x4*)(x + (size_t)bid * D + t * 4) = o;
  } else {
    int idx = (bid - 2048) * 256 + t;
    int h = idx >> 11;
    int dpos = idx & 2047;
    int delta = dpos - 1023;
    if (delta > 1023) delta = 1023;
    int side = (delta > 0) ? 16 : 0;
    int rp = (delta < 0) ? -delta : delta;
    int bucket;
    if (rp < 8) {
      bucket = side + rp;
    } else {
      float t3 = (logf((float)rp * 0.125f) / 2.7725887f) * 8.0f;
      int v = 8 + (int)t3;
      if (v > 15) v = 15;
      bucket = side + v;
    }
    table[idx] = rel_bias[bucket * 16 + h];
  }
}

// ---------------------------------------------------------------------------
// GEMM: C[M,N] = epilogue(A[M,K] @ W[N,K]^T over K-slice blockIdx.z).
// TBM in {64,128}, BN=128, BK=64, 4 waves (2x2), wave tile (TBM/2)x64.
// LDS: [row][8 chunks of 16B], physical chunk p holds source chunk p^(r&7)
// (source-side XOR swizzle; DMA dest stays linear). Fragment read at
// physical chunk (c*4+lq)^(r&7) -> conflict-free across all 32 banks.
// WF32: W fp32 via VGPR cvt (compact plan only); else bf16 DMA staging.
// W0/W1/W2 3-way select by out-col (QKV fusion; wsel_cols=1<<30 disables).
// OP: 0 = store, 2 = relu-store. Output bf16 at C + z*M*N.
// XCD stripe swizzle (gridDim.y % 8 == 0 in all launches).
// ---------------------------------------------------------------------------
template <int TBM, bool WF32, int OP>
__global__ __launch_bounds__(256, 3) void gemm_bt(
    const bf16_t* __restrict__ A, const void* __restrict__ W0,
    const void* __restrict__ W1, const void* __restrict__ W2,
    bf16_t* __restrict__ C, int M, int K_total, int klen, int N,
    int wsel_cols) {
  constexpr int MFRAG = TBM / 32;
  __shared__ bf16_t As[TBM * 64];
  __shared__ bf16_t Bs[128 * 64];

  const int tid = threadIdx.x;
  const int lane = tid & 63;
  const int wv = tid >> 6;
  const int wm = wv & 1;
  const int wn = wv >> 1;
  const int lr = lane & 15;
  const int lq = lane >> 4;

  int bx = blockIdx.x, by = blockIdx.y;
  {
    int gx = gridDim.x, gy = gridDim.y;
    int lid = by * gx + bx;
    int xcd = lid & 7, slot = lid >> 3;
    int per = gy >> 3;
    by = xcd * per + slot % per;
    bx = slot / per;
  }

  const size_t row0 = (size_t)bx * TBM;
  const size_t col0 = (size_t)by * 128;
  const int k0 = blockIdx.z * klen;

  const void* Ws = W0;
  size_t wc0 = col0;
  if ((int)col0 >= wsel_cols) {
    if ((int)col0 < 2 * wsel_cols) { Ws = W1; wc0 = col0 - wsel_cols; }
    else { Ws = W2; wc0 = col0 - 2 * (size_t)wsel_cols; }
  }

  const bf16_t* Abase = A + row0 * K_total;
  bf16_t* Cs = C + (size_t)blockIdx.z * M * N;

  floatx4 acc[MFRAG][4] = {};

  for (int kt = k0; kt < k0 + klen; kt += 64) {
#pragma unroll
    for (int i = 0; i < TBM / 32; ++i) {
      int chunk = i * 256 + tid;
      int r = chunk >> 3;
      int kc = ((chunk & 7) ^ (r & 7)) << 3;
      __builtin_amdgcn_global_load_lds(
          GLOBAL_AS(Abase + (size_t)r * K_total + kt + kc),
          LDS_AS(As + (size_t)(i * 256 + wv * 64) * 8), 16, 0, 0);
    }
    if constexpr (WF32) {
      const float* Wbase = (const float*)Ws + wc0 * K_total;
#pragma unroll
      for (int i = 0; i < 4; ++i) {
        int chunk = i * 256 + tid;
        int r = chunk >> 3;
        int kc = ((chunk & 7) ^ (r & 7)) << 3;
        const float* p = Wbase + (size_t)r * K_total + kt + kc;
        float4 f0 = *(const float4*)p;
        float4 f1v = *(const float4*)(p + 4);
        bf16x8 o;
        o[0] = (bf16_t)f0.x; o[1] = (bf16_t)f0.y;
        o[2] = (bf16_t)f0.z; o[3] = (bf16_t)f0.w;
        o[4] = (bf16_t)f1v.x; o[5] = (bf16_t)f1v.y;
        o[6] = (bf16_t)f1v.z; o[7] = (bf16_t)f1v.w;
        *(bf16x8*)(Bs + chunk * 8) = o;
      }
    } else {
      const bf16_t* Wbase = (const bf16_t*)Ws + wc0 * K_total;
#pragma unroll
      for (int i = 0; i < 4; ++i) {
        int chunk = i * 256 + tid;
        int r = chunk >> 3;
        int kc = ((chunk & 7) ^ (r & 7)) << 3;
        __builtin_amdgcn_global_load_lds(
            GLOBAL_AS(Wbase + (size_t)r * K_total + kt + kc),
            LDS_AS(Bs + (size_t)(i * 256 + wv * 64) * 8), 16, 0, 0);
      }
    }
    __syncthreads();

#pragma unroll
    for (int c = 0; c < 2; ++c) {
      bf16x8 af[MFRAG], bfr[4];
#pragma unroll
      for (int mi = 0; mi < MFRAG; ++mi) {
        int rr = wm * (TBM / 2) + mi * 16 + lr;
        int c8p = (c * 4 + lq) ^ (rr & 7);
        af[mi] = *(const bf16x8*)(As + rr * 64 + c8p * 8);
      }
#pragma unroll
      for (int nj = 0; nj < 4; ++nj) {
        int rr = wn * 64 + nj * 16 + lr;
        int c8p = (c * 4 + lq) ^ (rr & 7);
        bfr[nj] = *(const bf16x8*)(Bs + rr * 64 + c8p * 8);
      }
#pragma unroll
      for (int mi = 0; mi < MFRAG; ++mi)
#pragma unroll
        for (int nj = 0; nj < 4; ++nj)
          acc[mi][nj] = __builtin_amdgcn_mfma_f32_16x16x32_bf16(
              af[mi], bfr[nj], acc[mi][nj], 0, 0, 0);
    }
    __syncthreads();
  }

#pragma unroll
  for (int mi = 0; mi < MFRAG; ++mi) {
#pragma unroll
    for (int nj = 0; nj < 4; ++nj) {
      size_t r = row0 + wm * (TBM / 2) + mi * 16 + lq * 4;
      size_t c = col0 + wn * 64 + nj * 16 + lr;
#pragma unroll
      for (int t = 0; t < 4; ++t) {
        float v = acc[mi][nj][t];
        if (OP == 2) v = v > 0.f ? v : 0.f;
        Cs[(r + t) * N + c] = (bf16_t)v;
      }
    }
  }
}

// ---------------------------------------------------------------------------
// V transpose: qkv V-section [b,s,h,d] -> Vt_g[(b*16+h)*64 + d][s].
// ---------------------------------------------------------------------------
__global__ __launch_bounds__(256) void transpose_v_kernel(
    const bf16_t* __restrict__ QKV, bf16_t* __restrict__ VT) {
  __shared__ bf16_t T[64 * 65];
  const int s0 = blockIdx.x * 64;
  const int h = blockIdx.y;
  const int b = blockIdx.z;
  const int tid = threadIdx.x;

  const bf16_t* Vh = QKV + ((size_t)b * 1024) * 3072 + 2048 + h * 64;
#pragma unroll
  for (int i = 0; i < 2; ++i) {
    int c = i * 256 + tid;
    int r = c >> 3;
    int d8 = (c & 7) * 8;
    bf16x8 v = *(const bf16x8*)(Vh + (size_t)(s0 + r) * 3072 + d8);
#pragma unroll
    for (int j = 0; j < 8; ++j) T[r * 65 + d8 + j] = v[j];
  }
  __syncthreads();

  bf16_t* Og = VT + ((size_t)b * 16 + h) * 64 * 1024;
#pragma unroll
  for (int i = 0; i < 2; ++i) {
    int c = i * 256 + tid;
    int d = c >> 3;
    int s8 = (c & 7) * 8;
    bf16x8 o;
#pragma unroll
    for (int j = 0; j < 8; ++j) o[j] = T[(s8 + j) * 65 + d];
    *(bf16x8*)(Og + (size_t)d * 1024 + s0 + s8) = o;
  }
}

// ---------------------------------------------------------------------------
// Flash attention, T5 style.  Fragment-major LDS (conflict-free), S^T MFMA,
// constant-shift softmax.
// ---------------------------------------------------------------------------
__device__ __forceinline__ void attn_stage(const bf16_t* Kh, const bf16_t* Vg,
                                           int k0, bf16_t* Ksb, bf16_t* Vtb,
                                           int tid, int wv) {
  const int l16 = tid & 15;
  const int lo8 = ((tid & 63) >> 4) * 8;
#pragma unroll
  for (int i = 0; i < 2; ++i) {
    int bi = wv * 2 + i;
    int g = bi >> 1, c = bi & 1;
    __builtin_amdgcn_global_load_lds(
        GLOBAL_AS(Kh + (size_t)(k0 + g * 16 + l16) * 3072 + c * 32 + lo8),
        LDS_AS(Ksb + bi * 512), 16, 0, 0);
    __builtin_amdgcn_global_load_lds(
        GLOBAL_AS(Vg + (size_t)(g * 16 + l16) * 1024 + k0 + c * 32 + lo8),
        LDS_AS(Vtb + bi * 512), 16, 0, 0);
  }
}

__global__ __launch_bounds__(256) void attn_kernel(
    const bf16_t* __restrict__ QKV, const bf16_t* __restrict__ VT,
    const float* __restrict__ bias_table, bf16_t* __restrict__ O) {
  const int qt = blockIdx.x;
  const int h = blockIdx.y;
  const int b = blockIdx.z;
  const int tid = threadIdx.x;
  const int lane = tid & 63;
  const int wv = tid >> 6;
  const int lr = lane & 15;
  const int lq = lane >> 4;

  __shared__ bf16_t Ks[2][4096];
  __shared__ bf16_t Vt[2][4096];
  __shared__ bf16_t Ps[4][1024];

  const bf16_t* Qh = QKV + (size_t)b * 1024 * 3072 + h * 64;
  const bf16_t* Kh = Qh + 1024;
  const bf16_t* Vg = VT + ((size_t)b * 16 + h) * 64 * 1024;
  bf16_t* Oh = O + (size_t)b * 1024 * 1024 + h * 64;

  const int q0w = qt * 64 + wv * 16;
  const int myq = q0w + lr;

  bf16x8 qf[2];
#pragma unroll
  for (int c = 0; c < 2; ++c)
    qf[c] = *(const bf16x8*)(Qh + (size_t)(q0w + lr) * 3072 + c * 32 + lq * 8);

  float l_loc = 0.f;
  floatx4 o_acc[4];
#pragma unroll
  for (int i = 0; i < 4; ++i) o_acc[i] = (floatx4){0.f, 0.f, 0.f, 0.f};

  const float* btab = bias_table + h * 2048 + 1023 - myq;

  attn_stage(Kh, Vg, 0, Ks[0], Vt[0], tid, wv);
  __syncthreads();

  for (int kt = 0; kt < 16; ++kt) {
    const int k0 = kt * 64;
    if (kt < 15)
      attn_stage(Kh, Vg, k0 + 64, Ks[(kt + 1) & 1], Vt[(kt + 1) & 1], tid, wv);
    const bf16_t* Ksb = Ks[kt & 1];
    const bf16_t* Vtb = Vt[kt & 1];

    floatx4 s_acc[4];
#pragma unroll
    for (int g = 0; g < 4; ++g) {
      floatx4 a = (floatx4){0.f, 0.f, 0.f, 0.f};
#pragma unroll
      for (int c = 0; c < 2; ++c) {
        bf16x8 kf = *(const bf16x8*)(Ksb + (g * 2 + c) * 512 + lane * 8);
        a = __builtin_amdgcn_mfma_f32_16x16x32_bf16(kf, qf[c], a, 0, 0, 0);
      }
      s_acc[g] = a;
    }

#pragma unroll
    for (int g = 0; g < 4; ++g) {
      bf16x4 pb;
#pragma unroll
      for (int t = 0; t < 4; ++t) {
        int key = k0 + g * 16 + lq * 4 + t;
        float p = __expf(s_acc[g][t] + btab[key] - 32.0f);
        l_loc += p;
        pb[t] = (bf16_t)p;
      }
      int c = g >> 1;
      int dst = c * 512 + (((g & 1) * 2 + (lq >> 1)) * 16 + lr) * 8 + (lq & 1) * 4;
      *(bf16x4*)(&Ps[wv][dst]) = pb;
    }

    asm volatile("s_waitcnt lgkmcnt(0)" ::: "memory");

    bf16x8 pf[2];
#pragma unroll
    for (int c = 0; c < 2; ++c)
      pf[c] = *(const bf16x8*)(&Ps[wv][c * 512 + lane * 8]);

#pragma unroll
    for (int g = 0; g < 4; ++g) {
#pragma unroll
      for (int c = 0; c < 2; ++c) {
        bf16x8 vf = *(const bf16x8*)(Vtb + (g * 2 + c) * 512 + lane * 8);
        o_acc[g] = __builtin_amdgcn_mfma_f32_16x16x32_bf16(pf[c], vf, o_acc[g], 0, 0, 0);
      }
    }
    __syncthreads();
  }

  l_loc += __shfl_xor(l_loc, 16);
  l_loc += __shfl_xor(l_loc, 32);
  float inv = 1.f / l_loc;

  float invt[4];
#pragma unroll
  for (int t = 0; t < 4; ++t) invt[t] = __shfl(inv, lq * 4 + t);

#pragma unroll
  for (int g = 0; g < 4; ++g) {
#pragma unroll
    for (int t = 0; t < 4; ++t) {
      int qg = q0w + lq * 4 + t;
      int d = g * 16 + lr;
      Oh[(size_t)qg * 1024 + d] = (bf16_t)(o_acc[g][t] * invt[t]);
    }
  }
}

// ---------------------------------------------------------------------------
// Split-K reduce + fp32 residual + fused RMSNorm.
// ---------------------------------------------------------------------------
__global__ __launch_bounds__(256) void reduce_rms_kernel(
    const bf16_t* __restrict__ part, int splits, const float* __restrict__ hs,
    const float* __restrict__ ln2w, bf16_t* __restrict__ hbuf,
    bf16_t* __restrict__ y) {
  const size_t SLICE = (size_t)2048 * 1024;
  int tid = threadIdx.x;
  size_t i = ((size_t)blockIdx.x * 256 + tid) * 8;

  float s[8] = {};
  for (int sp = 0; sp < splits; ++sp) {
    bf16x8 p = *(const bf16x8*)(part + sp * SLICE + i);
#pragma unroll
    for (int j = 0; j < 8; ++j) s[j] += (float)p[j];
  }
  float4 a = *(const float4*)(hs + i);
  float4 b = *(const float4*)(hs + i + 4);
  s[0] += a.x; s[1] += a.y; s[2] += a.z; s[3] += a.w;
  s[4] += b.x; s[5] += b.y; s[6] += b.z; s[7] += b.w;

  bf16x8 hb;
#pragma unroll
  for (int j = 0; j < 8; ++j) hb[j] = (bf16_t)s[j];
  *(bf16x8*)(hbuf + i) = hb;

  float ss = 0.f;
#pragma unroll
  for (int j = 0; j < 8; ++j) ss += s[j] * s[j];
#pragma unroll
  for (int off = 32; off > 0; off >>= 1) ss += __shfl_down(ss, off);
  __shared__ float red[4];
  int wave = tid >> 6;
  if ((tid & 63) == 0) red[wave] = ss;
  __syncthreads();
  float rowss = (tid < 128) ? (red[0] + red[1]) : (red[2] + red[3]);
  float scale = rsqrtf(rowss * (1.f / 1024.f) + 1e-6f);

  int col = (int)(i & 1023);
  float4 w0 = *(const float4*)(ln2w + col);
  float4 w1 = *(const float4*)(ln2w + col + 4);
  bf16x8 o;
  o[0] = (bf16_t)(s[0] * scale * w0.x); o[1] = (bf16_t)(s[1] * scale * w0.y);
  o[2] = (bf16_t)(s[2] * scale * w0.z); o[3] = (bf16_t)(s[3] * scale * w0.w);
  o[4] = (bf16_t)(s[4] * scale * w1.x); o[5] = (bf16_t)(s[5] * scale * w1.y);
  o[6] = (bf16_t)(s[6] * scale * w1.z); o[7] = (bf16_t)(s[7] * scale * w1.w);
  *(bf16x8*)(y + i) = o;
}

// ---------------------------------------------------------------------------
// Final split-K reduce + bf16 residual -> fp32 output.
// ---------------------------------------------------------------------------
__global__ __launch_bounds__(256) void reduce_out_kernel(
    const bf16_t* __restrict__ part, int splits,
    const bf16_t* __restrict__ res, float* __restrict__ out) {
  const size_t SLICE = (size_t)2048 * 1024;
  size_t i = ((size_t)blockIdx.x * 256 + threadIdx.x) * 8;
  float s[8] = {};
  for (int sp = 0; sp < splits; ++sp) {
    bf16x8 p = *(const bf16x8*)(part + sp * SLICE + i);
#pragma unroll
    for (int j = 0; j < 8; ++j) s[j] += (float)p[j];
  }
  bf16x8 r = *(const bf16x8*)(res + i);
#pragma unroll
  for (int j = 0; j < 8; ++j) s[j] += (float)r[j];
  float4 a, b;
  a.x = s[0]; a.y = s[1]; a.z = s[2]; a.w = s[3];
  b.x = s[4]; b.y = s[5]; b.z = s[6]; b.w = s[7];
  *(float4*)(out + i) = a;
  *(float4*)(out + i + 4) = b;
}

// ---------------------------------------------------------------------------
extern "C" void kernel_launch(void* const* d_in, const int* in_sizes, int n_in,
                              void* d_out, int out_size, void* d_ws,
                              size_t ws_size, hipStream_t stream) {
  const float* hs = (const float*)d_in[0];
  const float* ln1_w = (const float*)d_in[1];
  const float* wq = (const float*)d_in[2];
  const float* wk = (const float*)d_in[3];
  const float* wvv = (const float*)d_in[4];
  const float* wo = (const float*)d_in[5];
  const float* rel_bias = (const float*)d_in[6];
  const float* ln2_w = (const float*)d_in[7];
  const float* wi = (const float*)d_in[8];
  const float* wo_ff = (const float*)d_in[9];
  float* out = (float*)d_out;

  const int M = 2048, D = 1024, FF = 4096;
  const size_t SL = (size_t)M * D * 2;       // 4 MB
  const size_t QKVB = (size_t)M * 3072 * 2;  // 12 MB
  const size_t F1B = (size_t)M * FF * 2;     // 16 MB
  const size_t BT = 16 * 2048 * 4;           // 128 KB

  // FULL: +bf16 weights (24 MB), part(4) -> 92.4 MB total
  const size_t FULL_NEED = BT + 6291456 + 2097152 + 8388608 + 8388608 +
                           SL + QKVB + SL + SL + SL + F1B + SL + 4 * SL;
  const size_t COMPACT_NEED = BT + SL + QKVB + F1B;  // 33,685,504 (proven)

  char* w = (char*)d_ws;
  dim3 gtv(16, 16, 2), ga(16, 16, 2);

  if (ws_size >= FULL_NEED) {
    float* btab = (float*)w;      w += BT;
    bf16_t* wqkv_b = (bf16_t*)w;  w += 6291456;
    bf16_t* wo_b = (bf16_t*)w;    w += 2097152;
    bf16_t* wi_b = (bf16_t*)w;    w += 8388608;
    bf16_t* woff_b = (bf16_t*)w;  w += 8388608;
    bf16_t* x = (bf16_t*)w;       w += SL;
    bf16_t* qkv = (bf16_t*)w;     w += QKVB;
    bf16_t* ctx = (bf16_t*)w;     w += SL;
    bf16_t* hbuf = (bf16_t*)w;    w += SL;
    bf16_t* y = (bf16_t*)w;       w += SL;
    bf16_t* f1 = (bf16_t*)w;      w += F1B;
    bf16_t* vtg = (bf16_t*)w;     w += SL;
    bf16_t* part = (bf16_t*)w;    w += 4 * SL;

    convert_w_kernel<<<6144, 256, 0, stream>>>(wq, wk, wvv, wo, wi, wo_ff,
                                               wqkv_b, wo_b, wi_b, woff_b);
    prologue_kernel<<<2176, 256, 0, stream>>>(hs, ln1_w, rel_bias, x, btab);

    // QKV: 128-tile, (16,24) = 384 blocks, bf16 W DMA
    gemm_bt<128, false, 0><<<dim3(16, 24, 1), 256, 0, stream>>>(
        x, wqkv_b, wqkv_b, wqkv_b, qkv, M, D, D, 3072, 1 << 30);
    transpose_v_kernel<<<gtv, 256, 0, stream>>>(qkv, vtg);
    attn_kernel<<<ga, 256, 0, stream>>>(qkv, vtg, btab, ctx);

    // WO: 128-tile split-K=4 -> (16,8,4) = 512 blocks
    gemm_bt<128, false, 0><<<dim3(16, 8, 4), 256, 0, stream>>>(
        ctx, wo_b, wo_b, wo_b, part, M, D, D / 4, D, 1 << 30);
    reduce_rms_kernel<<<1024, 256, 0, stream>>>(part, 4, hs, ln2_w, hbuf, y);

    // WI: 128-tile, (16,32) = 512 blocks
    gemm_bt<128, false, 2><<<dim3(16, 32, 1), 256, 0, stream>>>(
        y, wi_b, wi_b, wi_b, f1, M, D, D, FF, 1 << 30);

    // WO_FF: 128-tile split-K=4 -> 512 blocks
    gemm_bt<128, false, 0><<<dim3(16, 8, 4), 256, 0, stream>>>(
        f1, woff_b, woff_b, woff_b, part, M, FF, FF / 4, D, 1 << 30);
    reduce_out_kernel<<<1024, 256, 0, stream>>>(part, 4, hbuf, out);
  } else {
    if (ws_size < COMPACT_NEED) return;
    float* btab = (float*)w;  w += BT;
    char* Abuf = w;           w += SL;
    char* Bbuf = w;           w += QKVB;
    char* Fbuf = w;           w += F1B;
    bf16_t* x = (bf16_t*)Abuf;
    bf16_t* ctx = (bf16_t*)Abuf;
    bf16_t* hbuf = (bf16_t*)Abuf;
    bf16_t* qkv = (bf16_t*)Bbuf;
    bf16_t* part = (bf16_t*)Bbuf;
    bf16_t* y = (bf16_t*)(Bbuf + 2 * SL);
    bf16_t* vtg = (bf16_t*)Fbuf;
    bf16_t* f1 = (bf16_t*)Fbuf;

    prologue_kernel<<<2176, 256, 0, stream>>>(hs, ln1_w, rel_bias, x, btab);

    gemm_bt<64, true, 0><<<dim3(32, 24, 1), 256, 0, stream>>>(
        x, wq, wk, wvv, qkv, M, D, D, 3072, 1024);
    transpose_v_kernel<<<gtv, 256, 0, stream>>>(qkv, vtg);
    attn_kernel<<<ga, 256, 0, stream>>>(qkv, vtg, btab, ctx);

    gemm_bt<64, true, 0><<<dim3(32, 8, 2), 256, 0, stream>>>(
        ctx, wo, wo, wo, part, M, D, D / 2, D, 1 << 30);
    reduce_rms_kernel<<<1024, 256, 0, stream>>>(part, 2, hs, ln2_w, hbuf, y);

    gemm_bt<64, true, 2><<<dim3(32, 32, 1), 256, 0, stream>>>(
        y, wi, wi, wi, f1, M, D, D, FF, 1 << 30);

    gemm_bt<64, true, 0><<<dim3(32, 8, 2), 256, 0, stream>>>(
        f1, wo_ff, wo_ff, wo_ff, part, M, FF, FF / 2, D, 1 << 30);
    reduce_out_kernel<<<1024, 256, 0, stream>>>(part, 2, hbuf, out);
  }
}

// Round 12
// 228.536 us; speedup vs baseline: 1.2014x; 1.0194x over previous
//
#include <hip/hip_runtime.h>
#include <hip/hip_bf16.h>
#include <math.h>

// T5 encoder block on MI355X (gfx950). B=2, S=1024, D_MODEL=1024, H=16,
// D_KV=64, D_FF=4096. Harness buffers fp32 (ws=256MiB -> full plan).
// Internal bf16 MFMA, fp32 acc.
// ROUND 12: (1) QKV GEMM writes V directly TRANSPOSED from accumulators
// (kills transpose_v kernel + 12MB traffic); (2) coalesced GEMM epilogue
// via per-wave LDS repack (bf16x8 stores instead of 64 scalar shorts);
// (3) convert_w merged into the prologue launch.

typedef __bf16 bf16_t;
typedef __attribute__((ext_vector_type(8))) __bf16 bf16x8;
typedef __attribute__((ext_vector_type(4))) __bf16 bf16x4;
typedef __attribute__((ext_vector_type(4))) float floatx4;

#define GLOBAL_AS(p) ((const __attribute__((address_space(1))) void*)(p))
#define LDS_AS(p)    ((__attribute__((address_space(3))) void*)(p))

// ---------------------------------------------------------------------------
// Prologue: blocks [0,6144) convert weights fp32->bf16 (skipped when
// do_convert==0); [6144,8192) RMSNorm rows; [8192,8320) bias table.
// ---------------------------------------------------------------------------
__global__ __launch_bounds__(256) void prologue_kernel(
    const float* __restrict__ hs, const float* __restrict__ ln1w,
    const float* __restrict__ rel_bias, const float* __restrict__ wq,
    const float* __restrict__ wk, const float* __restrict__ wv,
    const float* __restrict__ wo, const float* __restrict__ wi,
    const float* __restrict__ woff, bf16_t* __restrict__ x,
    float* __restrict__ table, bf16_t* __restrict__ wqkv_b,
    bf16_t* __restrict__ wo_b, bf16_t* __restrict__ wi_b,
    bf16_t* __restrict__ woff_b, int do_convert) {
  int bid = blockIdx.x;
  int t = threadIdx.x;
  if (bid < 6144) {
    if (!do_convert) return;
    size_t idx = ((size_t)bid * 256 + t) * 8;
    const float* src;
    bf16_t* dst;
    size_t off;
    if (idx < 3145728) {
      size_t sec = idx >> 20;
      src = sec == 0 ? wq : (sec == 1 ? wk : wv);
      dst = wqkv_b + (sec << 20);
      off = idx & 1048575;
    } else if (idx < 4194304) {
      src = wo; dst = wo_b; off = idx - 3145728;
    } else if (idx < 8388608) {
      src = wi; dst = wi_b; off = idx - 4194304;
    } else {
      src = woff; dst = woff_b; off = idx - 8388608;
    }
    float4 a = *(const float4*)(src + off);
    float4 b = *(const float4*)(src + off + 4);
    bf16x8 o;
    o[0] = (bf16_t)a.x; o[1] = (bf16_t)a.y; o[2] = (bf16_t)a.z; o[3] = (bf16_t)a.w;
    o[4] = (bf16_t)b.x; o[5] = (bf16_t)b.y; o[6] = (bf16_t)b.z; o[7] = (bf16_t)b.w;
    *(bf16x8*)(dst + off) = o;
  } else if (bid < 8192) {
    int row = bid - 6144;
    const int D = 1024;
    float4 v = ((const float4*)(hs + (size_t)row * D))[t];
    float f[4] = {v.x, v.y, v.z, v.w};
    float s = 0.f;
#pragma unroll
    for (int j = 0; j < 4; ++j) s += f[j] * f[j];
#pragma unroll
    for (int off = 32; off > 0; off >>= 1) s += __shfl_down(s, off);
    __shared__ float red[4];
    int lane = t & 63, wave = t >> 6;
    if (lane == 0) red[wave] = s;
    __syncthreads();
    float tot = red[0] + red[1] + red[2] + red[3];
    float scale = rsqrtf(tot * (1.0f / D) + 1e-6f);
    float4 wv4 = ((const float4*)ln1w)[t];
    bf16x4 o;
    o[0] = (bf16_t)(f[0] * scale * wv4.x);
    o[1] = (bf16_t)(f[1] * scale * wv4.y);
    o[2] = (bf16_t)(f[2] * scale * wv4.z);
    o[3] = (bf16_t)(f[3] * scale * wv4.w);
    *(bf16x4*)(x + (size_t)row * D + t * 4) = o;
  } else {
    int idx = (bid - 8192) * 256 + t;
    int h = idx >> 11;
    int dpos = idx & 2047;
    int delta = dpos - 1023;
    if (delta > 1023) delta = 1023;
    int side = (delta > 0) ? 16 : 0;
    int rp = (delta < 0) ? -delta : delta;
    int bucket;
    if (rp < 8) {
      bucket = side + rp;
    } else {
      float t3 = (logf((float)rp * 0.125f) / 2.7725887f) * 8.0f;
      int v = 8 + (int)t3;
      if (v > 15) v = 15;
      bucket = side + v;
    }
    table[idx] = rel_bias[bucket * 16 + h];
  }
}

// ---------------------------------------------------------------------------
// GEMM: C[M,N] = epilogue(A[M,K] @ W[N,K]^T over K-slice blockIdx.z).
// TBM in {64,128}, BN=128, BK=64, 4 waves (2x2), wave tile (TBM/2)x64.
// Staging: source-side XOR swizzle -> conflict-free fragment ds_read_b128.
// Epilogue: col0 >= vtsel -> transposed bf16x4 scatter into VT (V^T[d][s]);
// else per-wave LDS repack -> coalesced bf16x8 row stores.
// WF32: W fp32 via VGPR cvt (compact plan); else bf16 DMA staging.
// OP: 0 = store, 2 = relu.  XCD stripe swizzle (gridDim.y % 8 == 0).
// ---------------------------------------------------------------------------
template <int TBM, bool WF32, int OP>
__global__ __launch_bounds__(256, 3) void gemm_bt(
    const bf16_t* __restrict__ A, const void* __restrict__ W0,
    const void* __restrict__ W1, const void* __restrict__ W2,
    bf16_t* __restrict__ C, bf16_t* __restrict__ VT, int M, int K_total,
    int klen, int N, int wsel_cols, int vtsel) {
  constexpr int MFRAG = TBM / 32;
  constexpr int WROWS = TBM / 2;
  __shared__ bf16_t buf[(TBM + 128) * 64];
  bf16_t* As = buf;
  bf16_t* Bs = buf + TBM * 64;

  const int tid = threadIdx.x;
  const int lane = tid & 63;
  const int wv = tid >> 6;
  const int wm = wv & 1;
  const int wn = wv >> 1;
  const int lr = lane & 15;
  const int lq = lane >> 4;

  int bx = blockIdx.x, by = blockIdx.y;
  {
    int gx = gridDim.x, gy = gridDim.y;
    int lid = by * gx + bx;
    int xcd = lid & 7, slot = lid >> 3;
    int per = gy >> 3;
    by = xcd * per + slot % per;
    bx = slot / per;
  }

  const size_t row0 = (size_t)bx * TBM;
  const size_t col0 = (size_t)by * 128;
  const int k0 = blockIdx.z * klen;

  const void* Ws = W0;
  size_t wc0 = col0;
  if ((int)col0 >= wsel_cols) {
    if ((int)col0 < 2 * wsel_cols) { Ws = W1; wc0 = col0 - wsel_cols; }
    else { Ws = W2; wc0 = col0 - 2 * (size_t)wsel_cols; }
  }

  const bf16_t* Abase = A + row0 * K_total;
  bf16_t* Cs = C + (size_t)blockIdx.z * M * N;

  floatx4 acc[MFRAG][4] = {};

  for (int kt = k0; kt < k0 + klen; kt += 64) {
#pragma unroll
    for (int i = 0; i < TBM / 32; ++i) {
      int chunk = i * 256 + tid;
      int r = chunk >> 3;
      int kc = ((chunk & 7) ^ (r & 7)) << 3;
      __builtin_amdgcn_global_load_lds(
          GLOBAL_AS(Abase + (size_t)r * K_total + kt + kc),
          LDS_AS(As + (size_t)(i * 256 + wv * 64) * 8), 16, 0, 0);
    }
    if constexpr (WF32) {
      const float* Wbase = (const float*)Ws + wc0 * K_total;
#pragma unroll
      for (int i = 0; i < 4; ++i) {
        int chunk = i * 256 + tid;
        int r = chunk >> 3;
        int kc = ((chunk & 7) ^ (r & 7)) << 3;
        const float* p = Wbase + (size_t)r * K_total + kt + kc;
        float4 f0 = *(const float4*)p;
        float4 f1v = *(const float4*)(p + 4);
        bf16x8 o;
        o[0] = (bf16_t)f0.x; o[1] = (bf16_t)f0.y;
        o[2] = (bf16_t)f0.z; o[3] = (bf16_t)f0.w;
        o[4] = (bf16_t)f1v.x; o[5] = (bf16_t)f1v.y;
        o[6] = (bf16_t)f1v.z; o[7] = (bf16_t)f1v.w;
        *(bf16x8*)(Bs + chunk * 8) = o;
      }
    } else {
      const bf16_t* Wbase = (const bf16_t*)Ws + wc0 * K_total;
#pragma unroll
      for (int i = 0; i < 4; ++i) {
        int chunk = i * 256 + tid;
        int r = chunk >> 3;
        int kc = ((chunk & 7) ^ (r & 7)) << 3;
        __builtin_amdgcn_global_load_lds(
            GLOBAL_AS(Wbase + (size_t)r * K_total + kt + kc),
            LDS_AS(Bs + (size_t)(i * 256 + wv * 64) * 8), 16, 0, 0);
      }
    }
    __syncthreads();

#pragma unroll
    for (int c = 0; c < 2; ++c) {
      bf16x8 af[MFRAG], bfr[4];
#pragma unroll
      for (int mi = 0; mi < MFRAG; ++mi) {
        int rr = wm * WROWS + mi * 16 + lr;
        int c8p = (c * 4 + lq) ^ (rr & 7);
        af[mi] = *(const bf16x8*)(As + rr * 64 + c8p * 8);
      }
#pragma unroll
      for (int nj = 0; nj < 4; ++nj) {
        int rr = wn * 64 + nj * 16 + lr;
        int c8p = (c * 4 + lq) ^ (rr & 7);
        bfr[nj] = *(const bf16x8*)(Bs + rr * 64 + c8p * 8);
      }
#pragma unroll
      for (int mi = 0; mi < MFRAG; ++mi)
#pragma unroll
        for (int nj = 0; nj < 4; ++nj)
          acc[mi][nj] = __builtin_amdgcn_mfma_f32_16x16x32_bf16(
              af[mi], bfr[nj], acc[mi][nj], 0, 0, 0);
    }
    __syncthreads();
  }

  if ((int)col0 >= vtsel) {
    // V blocks: transposed scatter; lane rows = consecutive s, col = fixed d
    int b = (int)(row0 >> 10);
#pragma unroll
    for (int mi = 0; mi < MFRAG; ++mi) {
#pragma unroll
      for (int nj = 0; nj < 4; ++nj) {
        int d = (int)col0 - 2048 + wn * 64 + nj * 16 + lr;
        int h = d >> 6, dd = d & 63;
        int r = (int)row0 + wm * WROWS + mi * 16 + lq * 4;
        int s = r & 1023;
        bf16x4 pv;
#pragma unroll
        for (int t = 0; t < 4; ++t) pv[t] = (bf16_t)acc[mi][nj][t];
        *(bf16x4*)(VT + (((size_t)b * 16 + h) * 64 + dd) * 1024 + s) = pv;
      }
    }
  } else {
    // LDS repack -> coalesced row stores (wave-private region of buf)
    bf16_t* wbuf = buf + wv * (WROWS * 64);
#pragma unroll
    for (int mi = 0; mi < MFRAG; ++mi) {
#pragma unroll
      for (int nj = 0; nj < 4; ++nj) {
#pragma unroll
        for (int t = 0; t < 4; ++t) {
          float v = acc[mi][nj][t];
          if (OP == 2) v = v > 0.f ? v : 0.f;
          wbuf[(mi * 16 + lq * 4 + t) * 64 + nj * 16 + lr] = (bf16_t)v;
        }
      }
    }
    asm volatile("s_waitcnt lgkmcnt(0)" ::: "memory");  // wave-local RAW
#pragma unroll
    for (int p = 0; p < WROWS / 8; ++p) {
      int i = p * 8 + (lane >> 3);
      int cc = (lane & 7) * 8;
      bf16x8 vvv = *(const bf16x8*)(wbuf + i * 64 + cc);
      size_t gr = row0 + wm * WROWS + i;
      *(bf16x8*)(Cs + gr * N + col0 + wn * 64 + cc) = vvv;
    }
  }
}

// ---------------------------------------------------------------------------
// V transpose (compact path only).
// ---------------------------------------------------------------------------
__global__ __launch_bounds__(256) void transpose_v_kernel(
    const bf16_t* __restrict__ QKV, bf16_t* __restrict__ VT) {
  __shared__ bf16_t T[64 * 65];
  const int s0 = blockIdx.x * 64;
  const int h = blockIdx.y;
  const int b = blockIdx.z;
  const int tid = threadIdx.x;

  const bf16_t* Vh = QKV + ((size_t)b * 1024) * 3072 + 2048 + h * 64;
#pragma unroll
  for (int i = 0; i < 2; ++i) {
    int c = i * 256 + tid;
    int r = c >> 3;
    int d8 = (c & 7) * 8;
    bf16x8 v = *(const bf16x8*)(Vh + (size_t)(s0 + r) * 3072 + d8);
#pragma unroll
    for (int j = 0; j < 8; ++j) T[r * 65 + d8 + j] = v[j];
  }
  __syncthreads();

  bf16_t* Og = VT + ((size_t)b * 16 + h) * 64 * 1024;
#pragma unroll
  for (int i = 0; i < 2; ++i) {
    int c = i * 256 + tid;
    int d = c >> 3;
    int s8 = (c & 7) * 8;
    bf16x8 o;
#pragma unroll
    for (int j = 0; j < 8; ++j) o[j] = T[(s8 + j) * 65 + d];
    *(bf16x8*)(Og + (size_t)d * 1024 + s0 + s8) = o;
  }
}

// ---------------------------------------------------------------------------
// Flash attention, T5 style (fragment-major LDS, S^T MFMA, shift softmax).
// ---------------------------------------------------------------------------
__device__ __forceinline__ void attn_stage(const bf16_t* Kh, const bf16_t* Vg,
                                           int k0, bf16_t* Ksb, bf16_t* Vtb,
                                           int tid, int wv) {
  const int l16 = tid & 15;
  const int lo8 = ((tid & 63) >> 4) * 8;
#pragma unroll
  for (int i = 0; i < 2; ++i) {
    int bi = wv * 2 + i;
    int g = bi >> 1, c = bi & 1;
    __builtin_amdgcn_global_load_lds(
        GLOBAL_AS(Kh + (size_t)(k0 + g * 16 + l16) * 3072 + c * 32 + lo8),
        LDS_AS(Ksb + bi * 512), 16, 0, 0);
    __builtin_amdgcn_global_load_lds(
        GLOBAL_AS(Vg + (size_t)(g * 16 + l16) * 1024 + k0 + c * 32 + lo8),
        LDS_AS(Vtb + bi * 512), 16, 0, 0);
  }
}

__global__ __launch_bounds__(256) void attn_kernel(
    const bf16_t* __restrict__ QKV, const bf16_t* __restrict__ VT,
    const float* __restrict__ bias_table, bf16_t* __restrict__ O) {
  const int qt = blockIdx.x;
  const int h = blockIdx.y;
  const int b = blockIdx.z;
  const int tid = threadIdx.x;
  const int lane = tid & 63;
  const int wv = tid >> 6;
  const int lr = lane & 15;
  const int lq = lane >> 4;

  __shared__ bf16_t Ks[2][4096];
  __shared__ bf16_t Vt[2][4096];
  __shared__ bf16_t Ps[4][1024];

  const bf16_t* Qh = QKV + (size_t)b * 1024 * 3072 + h * 64;
  const bf16_t* Kh = Qh + 1024;
  const bf16_t* Vg = VT + ((size_t)b * 16 + h) * 64 * 1024;
  bf16_t* Oh = O + (size_t)b * 1024 * 1024 + h * 64;

  const int q0w = qt * 64 + wv * 16;
  const int myq = q0w + lr;

  bf16x8 qf[2];
#pragma unroll
  for (int c = 0; c < 2; ++c)
    qf[c] = *(const bf16x8*)(Qh + (size_t)(q0w + lr) * 3072 + c * 32 + lq * 8);

  float l_loc = 0.f;
  floatx4 o_acc[4];
#pragma unroll
  for (int i = 0; i < 4; ++i) o_acc[i] = (floatx4){0.f, 0.f, 0.f, 0.f};

  const float* btab = bias_table + h * 2048 + 1023 - myq;

  attn_stage(Kh, Vg, 0, Ks[0], Vt[0], tid, wv);
  __syncthreads();

  for (int kt = 0; kt < 16; ++kt) {
    const int k0 = kt * 64;
    if (kt < 15)
      attn_stage(Kh, Vg, k0 + 64, Ks[(kt + 1) & 1], Vt[(kt + 1) & 1], tid, wv);
    const bf16_t* Ksb = Ks[kt & 1];
    const bf16_t* Vtb = Vt[kt & 1];

    floatx4 s_acc[4];
#pragma unroll
    for (int g = 0; g < 4; ++g) {
      floatx4 a = (floatx4){0.f, 0.f, 0.f, 0.f};
#pragma unroll
      for (int c = 0; c < 2; ++c) {
        bf16x8 kf = *(const bf16x8*)(Ksb + (g * 2 + c) * 512 + lane * 8);
        a = __builtin_amdgcn_mfma_f32_16x16x32_bf16(kf, qf[c], a, 0, 0, 0);
      }
      s_acc[g] = a;
    }

#pragma unroll
    for (int g = 0; g < 4; ++g) {
      bf16x4 pb;
#pragma unroll
      for (int t = 0; t < 4; ++t) {
        int key = k0 + g * 16 + lq * 4 + t;
        float p = __expf(s_acc[g][t] + btab[key] - 32.0f);
        l_loc += p;
        pb[t] = (bf16_t)p;
      }
      int c = g >> 1;
      int dst = c * 512 + (((g & 1) * 2 + (lq >> 1)) * 16 + lr) * 8 + (lq & 1) * 4;
      *(bf16x4*)(&Ps[wv][dst]) = pb;
    }

    asm volatile("s_waitcnt lgkmcnt(0)" ::: "memory");

    bf16x8 pf[2];
#pragma unroll
    for (int c = 0; c < 2; ++c)
      pf[c] = *(const bf16x8*)(&Ps[wv][c * 512 + lane * 8]);

#pragma unroll
    for (int g = 0; g < 4; ++g) {
#pragma unroll
      for (int c = 0; c < 2; ++c) {
        bf16x8 vf = *(const bf16x8*)(Vtb + (g * 2 + c) * 512 + lane * 8);
        o_acc[g] = __builtin_amdgcn_mfma_f32_16x16x32_bf16(pf[c], vf, o_acc[g], 0, 0, 0);
      }
    }
    __syncthreads();
  }

  l_loc += __shfl_xor(l_loc, 16);
  l_loc += __shfl_xor(l_loc, 32);
  float inv = 1.f / l_loc;

  float invt[4];
#pragma unroll
  for (int t = 0; t < 4; ++t) invt[t] = __shfl(inv, lq * 4 + t);

#pragma unroll
  for (int g = 0; g < 4; ++g) {
#pragma unroll
    for (int t = 0; t < 4; ++t) {
      int qg = q0w + lq * 4 + t;
      int d = g * 16 + lr;
      Oh[(size_t)qg * 1024 + d] = (bf16_t)(o_acc[g][t] * invt[t]);
    }
  }
}

// ---------------------------------------------------------------------------
// Split-K reduce + fp32 residual + fused RMSNorm.
// ---------------------------------------------------------------------------
__global__ __launch_bounds__(256) void reduce_rms_kernel(
    const bf16_t* __restrict__ part, int splits, const float* __restrict__ hs,
    const float* __restrict__ ln2w, bf16_t* __restrict__ hbuf,
    bf16_t* __restrict__ y) {
  const size_t SLICE = (size_t)2048 * 1024;
  int tid = threadIdx.x;
  size_t i = ((size_t)blockIdx.x * 256 + tid) * 8;

  float s[8] = {};
  for (int sp = 0; sp < splits; ++sp) {
    bf16x8 p = *(const bf16x8*)(part + sp * SLICE + i);
#pragma unroll
    for (int j = 0; j < 8; ++j) s[j] += (float)p[j];
  }
  float4 a = *(const float4*)(hs + i);
  float4 b = *(const float4*)(hs + i + 4);
  s[0] += a.x; s[1] += a.y; s[2] += a.z; s[3] += a.w;
  s[4] += b.x; s[5] += b.y; s[6] += b.z; s[7] += b.w;

  bf16x8 hb;
#pragma unroll
  for (int j = 0; j < 8; ++j) hb[j] = (bf16_t)s[j];
  *(bf16x8*)(hbuf + i) = hb;

  float ss = 0.f;
#pragma unroll
  for (int j = 0; j < 8; ++j) ss += s[j] * s[j];
#pragma unroll
  for (int off = 32; off > 0; off >>= 1) ss += __shfl_down(ss, off);
  __shared__ float red[4];
  int wave = tid >> 6;
  if ((tid & 63) == 0) red[wave] = ss;
  __syncthreads();
  float rowss = (tid < 128) ? (red[0] + red[1]) : (red[2] + red[3]);
  float scale = rsqrtf(rowss * (1.f / 1024.f) + 1e-6f);

  int col = (int)(i & 1023);
  float4 w0 = *(const float4*)(ln2w + col);
  float4 w1 = *(const float4*)(ln2w + col + 4);
  bf16x8 o;
  o[0] = (bf16_t)(s[0] * scale * w0.x); o[1] = (bf16_t)(s[1] * scale * w0.y);
  o[2] = (bf16_t)(s[2] * scale * w0.z); o[3] = (bf16_t)(s[3] * scale * w0.w);
  o[4] = (bf16_t)(s[4] * scale * w1.x); o[5] = (bf16_t)(s[5] * scale * w1.y);
  o[6] = (bf16_t)(s[6] * scale * w1.z); o[7] = (bf16_t)(s[7] * scale * w1.w);
  *(bf16x8*)(y + i) = o;
}

// ---------------------------------------------------------------------------
// Final split-K reduce + bf16 residual -> fp32 output.
// ---------------------------------------------------------------------------
__global__ __launch_bounds__(256) void reduce_out_kernel(
    const bf16_t* __restrict__ part, int splits,
    const bf16_t* __restrict__ res, float* __restrict__ out) {
  const size_t SLICE = (size_t)2048 * 1024;
  size_t i = ((size_t)blockIdx.x * 256 + threadIdx.x) * 8;
  float s[8] = {};
  for (int sp = 0; sp < splits; ++sp) {
    bf16x8 p = *(const bf16x8*)(part + sp * SLICE + i);
#pragma unroll
    for (int j = 0; j < 8; ++j) s[j] += (float)p[j];
  }
  bf16x8 r = *(const bf16x8*)(res + i);
#pragma unroll
  for (int j = 0; j < 8; ++j) s[j] += (float)r[j];
  float4 a, b;
  a.x = s[0]; a.y = s[1]; a.z = s[2]; a.w = s[3];
  b.x = s[4]; b.y = s[5]; b.z = s[6]; b.w = s[7];
  *(float4*)(out + i) = a;
  *(float4*)(out + i + 4) = b;
}

// ---------------------------------------------------------------------------
extern "C" void kernel_launch(void* const* d_in, const int* in_sizes, int n_in,
                              void* d_out, int out_size, void* d_ws,
                              size_t ws_size, hipStream_t stream) {
  const float* hs = (const float*)d_in[0];
  const float* ln1_w = (const float*)d_in[1];
  const float* wq = (const float*)d_in[2];
  const float* wk = (const float*)d_in[3];
  const float* wvv = (const float*)d_in[4];
  const float* wo = (const float*)d_in[5];
  const float* rel_bias = (const float*)d_in[6];
  const float* ln2_w = (const float*)d_in[7];
  const float* wi = (const float*)d_in[8];
  const float* wo_ff = (const float*)d_in[9];
  float* out = (float*)d_out;

  const int M = 2048, D = 1024, FF = 4096;
  const size_t SL = (size_t)M * D * 2;       // 4 MB
  const size_t QKVB = (size_t)M * 3072 * 2;  // 12 MB
  const size_t F1B = (size_t)M * FF * 2;     // 16 MB
  const size_t BT = 16 * 2048 * 4;           // 128 KB
  const int NOVT = 1 << 30;

  const size_t FULL_NEED = BT + 6291456 + 2097152 + 8388608 + 8388608 +
                           SL + QKVB + SL + SL + SL + F1B + SL + 4 * SL;
  const size_t COMPACT_NEED = BT + SL + QKVB + F1B;  // 33,685,504 (proven)

  char* w = (char*)d_ws;
  dim3 ga(16, 16, 2);

  if (ws_size >= FULL_NEED) {
    float* btab = (float*)w;      w += BT;
    bf16_t* wqkv_b = (bf16_t*)w;  w += 6291456;
    bf16_t* wo_b = (bf16_t*)w;    w += 2097152;
    bf16_t* wi_b = (bf16_t*)w;    w += 8388608;
    bf16_t* woff_b = (bf16_t*)w;  w += 8388608;
    bf16_t* x = (bf16_t*)w;       w += SL;
    bf16_t* qkv = (bf16_t*)w;     w += QKVB;
    bf16_t* ctx = (bf16_t*)w;     w += SL;
    bf16_t* hbuf = (bf16_t*)w;    w += SL;
    bf16_t* y = (bf16_t*)w;       w += SL;
    bf16_t* f1 = (bf16_t*)w;      w += F1B;
    bf16_t* vtg = (bf16_t*)w;     w += SL;
    bf16_t* part = (bf16_t*)w;    w += 4 * SL;

    prologue_kernel<<<8320, 256, 0, stream>>>(
        hs, ln1_w, rel_bias, wq, wk, wvv, wo, wi, wo_ff, x, btab, wqkv_b,
        wo_b, wi_b, woff_b, 1);

    // QKV: (16,24)=384 blocks; V blocks (col0>=2048) write vtg transposed
    gemm_bt<128, false, 0><<<dim3(16, 24, 1), 256, 0, stream>>>(
        x, wqkv_b, wqkv_b, wqkv_b, qkv, vtg, M, D, D, 3072, NOVT, 2048);
    attn_kernel<<<ga, 256, 0, stream>>>(qkv, vtg, btab, ctx);

    gemm_bt<128, false, 0><<<dim3(16, 8, 4), 256, 0, stream>>>(
        ctx, wo_b, wo_b, wo_b, part, nullptr, M, D, D / 4, D, NOVT, NOVT);
    reduce_rms_kernel<<<1024, 256, 0, stream>>>(part, 4, hs, ln2_w, hbuf, y);

    gemm_bt<128, false, 2><<<dim3(16, 32, 1), 256, 0, stream>>>(
        y, wi_b, wi_b, wi_b, f1, nullptr, M, D, D, FF, NOVT, NOVT);

    gemm_bt<128, false, 0><<<dim3(16, 8, 4), 256, 0, stream>>>(
        f1, woff_b, woff_b, woff_b, part, nullptr, M, FF, FF / 4, D, NOVT,
        NOVT);
    reduce_out_kernel<<<1024, 256, 0, stream>>>(part, 4, hbuf, out);
  } else {
    if (ws_size < COMPACT_NEED) return;
    float* btab = (float*)w;  w += BT;
    char* Abuf = w;           w += SL;
    char* Bbuf = w;           w += QKVB;
    char* Fbuf = w;           w += F1B;
    bf16_t* x = (bf16_t*)Abuf;
    bf16_t* ctx = (bf16_t*)Abuf;
    bf16_t* hbuf = (bf16_t*)Abuf;
    bf16_t* qkv = (bf16_t*)Bbuf;
    bf16_t* part = (bf16_t*)Bbuf;
    bf16_t* y = (bf16_t*)(Bbuf + 2 * SL);
    bf16_t* vtg = (bf16_t*)Fbuf;
    bf16_t* f1 = (bf16_t*)Fbuf;

    prologue_kernel<<<8320, 256, 0, stream>>>(
        hs, ln1_w, rel_bias, wq, wk, wvv, wo, wi, wo_ff, x, btab, nullptr,
        nullptr, nullptr, nullptr, 0);

    gemm_bt<64, true, 0><<<dim3(32, 24, 1), 256, 0, stream>>>(
        x, wq, wk, wvv, qkv, nullptr, M, D, D, 3072, 1024, NOVT);
    transpose_v_kernel<<<dim3(16, 16, 2), 256, 0, stream>>>(qkv, vtg);
    attn_kernel<<<ga, 256, 0, stream>>>(qkv, vtg, btab, ctx);

    gemm_bt<64, true, 0><<<dim3(32, 8, 2), 256, 0, stream>>>(
        ctx, wo, wo, wo, part, nullptr, M, D, D / 2, D, NOVT, NOVT);
    reduce_rms_kernel<<<1024, 256, 0, stream>>>(part, 2, hs, ln2_w, hbuf, y);

    gemm_bt<64, true, 2><<<dim3(32, 32, 1), 256, 0, stream>>>(
        y, wi, wi, wi, f1, nullptr, M, D, D, FF, NOVT, NOVT);

    gemm_bt<64, true, 0><<<dim3(32, 8, 2), 256, 0, stream>>>(
        f1, wo_ff, wo_ff, wo_ff, part, nullptr, M, FF, FF / 2, D, NOVT,
        NOVT);
    reduce_out_kernel<<<1024, 256, 0, stream>>>(part, 2, hbuf, out);
  }
}